// Round 11
// baseline (153.639 us; speedup 1.0000x reference)
//
#include <hip/hip_runtime.h>

// DeformConv fused fp16: 2-barrier/tap double-buffered phase 3.
// Every barrier window mixes MFMA + gather-issue + combine (pipe overlap
// within a wave), vs the old 4-barrier pipe-pure convoy.
// B=4, C=128, H=W=96, O=128, 3x3 s1 p1 d1, G=1.
#define CIN   128
#define HH    96
#define WW    96
#define OUTC  128
#define HWSZ  9216
#define KK    9
#define KTOT  1152        // k' = tap*128 + c (tap-major)

typedef _Float16 f16x8 __attribute__((ext_vector_type(8)));
typedef _Float16 h2    __attribute__((ext_vector_type(2)));
typedef float    f32x4 __attribute__((ext_vector_type(4)));

__device__ __forceinline__ unsigned short f2h(float f) {
  _Float16 h = (_Float16)f;                      // v_cvt_f16_f32 (RNE)
  return __builtin_bit_cast(unsigned short, h);
}
// pack two floats to f16x2 (RTZ) : 1 VALU
__device__ __forceinline__ unsigned pack_h(float v0, float v1) {
  auto r = __builtin_amdgcn_cvt_pkrtz(v0, v1);   // lo = v0, hi = v1
  return __builtin_bit_cast(unsigned, r);
}

// ws layout (u16 offsets):
//   wtb   f16[128][1152] @ 0         (k' = tap*128+c)
//   wt2b  f16[32][1152]  @ 147456    (oc 0-17 offset, 18-26 mask, 27-31 zero)
//   bias32 f32[32]       @ 184320
//   xn    f16[4][9216][128] @ 184384 (NHWC)
//   x2n   f16[4][9216][128] @ 184384+4718592
#define WT2B_O 147456
#define BIAS_O 184320
#define XN_O   184384
#define X2N_O  (184384 + 4718592)

// Combined prep: blocks [0,1152) = NCHW->NHWC f16 transpose of x/x2
// (float4 loads: 4 px/lane, 16 c-rows/pass; uint4 stores);
// blocks [1152,1873) = weight reorder/cast.
__global__ __launch_bounds__(256) void prep_all(
    const float* __restrict__ x, const float* __restrict__ x2,
    const float* __restrict__ offw, const float* __restrict__ maskw,
    const float* __restrict__ defw, const float* __restrict__ offb,
    const float* __restrict__ maskb, void* __restrict__ wsv) {
  int bid = blockIdx.x;
  int t = threadIdx.x;
  if (bid < 1152) {
    // u16 tile[64 px][136] (word stride 68): word (c>>1) holds {c, c+1}
    __shared__ unsigned short tile[64][136];
    int tsel = bid / 576;
    int rem = bid - tsel * 576;
    int b = rem / 144;
    int hw0 = (rem % 144) * 64;
    const float* src = tsel ? x2 : x;
    unsigned short* dst = (unsigned short*)wsv + (tsel ? X2N_O : XN_O);
    unsigned* tw = (unsigned*)&tile[0][0];
    int c2  = t & 15;        // channel-pair index within pass
    int px4 = t >> 4;        // 0..15 -> px = px4*4..+3
#pragma unroll
    for (int pass = 0; pass < 4; ++pass) {
      int c = pass * 32 + c2 * 2;
      const float* r0 = src + ((size_t)(b * CIN + c)) * HWSZ + hw0 + px4 * 4;
      float4 f0 = *(const float4*)r0;          // 4 px of channel c
      float4 f1 = *(const float4*)(r0 + HWSZ); // 4 px of channel c+1
      int wb = pass * 16 + c2;                 // = c>>1
      tw[(px4 * 4 + 0) * 68 + wb] = pack_h(f0.x, f1.x);
      tw[(px4 * 4 + 1) * 68 + wb] = pack_h(f0.y, f1.y);
      tw[(px4 * 4 + 2) * 68 + wb] = pack_h(f0.z, f1.z);
      tw[(px4 * 4 + 3) * 68 + wb] = pack_h(f0.w, f1.w);
    }
    __syncthreads();
    unsigned* drow = (unsigned*)(dst + ((size_t)(b * HWSZ + hw0)) * 128);
    int w4 = t & 15, pxr = t >> 4;
#pragma unroll
    for (int pass = 0; pass < 4; ++pass) {
      int px = pass * 16 + pxr;
      uint4 v = *(const uint4*)&tw[px * 68 + w4 * 4];
      *(uint4*)&drow[(size_t)px * 64 + w4 * 4] = v;
    }
    return;
  }
  unsigned short* wtb  = (unsigned short*)wsv;
  unsigned short* wt2b = wtb + WT2B_O;
  float* bias32 = (float*)(wtb + BIAS_O);
  int idx = (bid - 1152) * 256 + t;
  if (idx < OUTC * KTOT) {
    int o = idx / KTOT, r = idx - o * KTOT;
    int c = r / KK, tap = r - c * KK;
    wtb[o * KTOT + tap * 128 + c] = f2h(defw[idx]);
  } else if (idx < OUTC * KTOT + 32 * KTOT) {
    int j = idx - OUTC * KTOT;
    int oc = j / KTOT, r = j - oc * KTOT;
    int c = r / KK, tap = r - c * KK;
    float v = 0.f;
    if (oc < 18)      v = offw[j];
    else if (oc < 27) v = maskw[j - 18 * KTOT];
    wt2b[oc * KTOT + tap * 128 + c] = f2h(v);
  } else if (idx < OUTC * KTOT + 32 * KTOT + 32) {
    int j = idx - OUTC * KTOT - 32 * KTOT;
    float v = 0.f;
    if (j < 18) v = offb[j]; else if (j < 27) v = maskb[j - 18];
    bias32[j] = v;
  }
}

// Fused: block = 64-px strip.
// Gather roles: wave w gathers px strip w*16..+15, lanes (quad = px-in-group,
// l15 = channel octet) -> full 256B row reads (4 segments/instr),
// corners combined in-lane with v_pk_fma_f16, written to val.
// Phase-3: 2x2 wave grid (mw=w&1, nw=w>>1); double-buffered B (bwA = oc 0..63,
// bwB = oc 64..127); 2 barriers/tap:
//   W1: af-read(t) | mfma0(t)@bwA | stage1(t)->bwB
//   W2: gather(t+1) | mfma1(t)@bwB | combine(t+1) | val-write(t+1) | stage0->bwA
// All val/bwA/bwB hazards are one-barrier-separated (audited).
// om aliases val (live only phase1end->phase2end). Direct f32x4 epilogue.
__global__ __launch_bounds__(256, 2) void fused(
    const float* __restrict__ defb, const void* __restrict__ wsv,
    float* __restrict__ out) {
  const unsigned short* wtb  = (const unsigned short*)wsv;
  const unsigned short* wt2b = wtb + WT2B_O;
  const float* bias32 = (const float*)(wtb + BIAS_O);
  const unsigned short* xn  = wtb + XN_O;
  const unsigned short* x2n = wtb + X2N_O;

  __shared__ unsigned bwA[64 * 68];        // 17.4 KB: B half (oc 0..63)
  __shared__ unsigned bwB[64 * 68];        // 17.4 KB: B half (oc 64..127)
  __shared__ unsigned short val[64][136];  // 17.4 KB: A tile (f16), pad 136
  __shared__ unsigned sidxw[KK * 4 * 64];  // 9.2 KB: [(tap*4+cr)*64+px] idx|w<<16
  float* om = (float*)&val[0][0];          // alias: om[oc*68+pp], 8.7 KB

  int t = threadIdx.x;
  int w = t >> 6;
  int mw = w & 1, nw = w >> 1;             // phase-3 2x2 wave grid
  int l15 = t & 15, quad = (t >> 4) & 3;
  int rb = blockIdx.x;
  int bid = (rb & 7) * 72 + (rb >> 3);     // XCD swizzle
  int b = bid / 144;
  int pblk = (bid % 144) * 64;

  // gather-role pixels: px = 16w + G*4 + quad
  int phg[4], pwg[4];
#pragma unroll
  for (int G = 0; G < 4; ++G) {
    int p = pblk + w * 16 + G * 4 + quad;
    phg[G] = p / WW;
    pwg[G] = p - phg[G] * WW;
  }

  // ===== phase 1: offset/mask GEMM (uses bwA) =====
  f32x4 oa0 = {0.f, 0.f, 0.f, 0.f};
  f32x4 oa1 = {0.f, 0.f, 0.f, 0.f};
  const unsigned short* x2nb = x2n + ((size_t)b * HWSZ) * 128;
  for (int tap = 0; tap < KK; ++tap) {
    int ky = tap / 3 - 1, kx = tap % 3 - 1;
    uint4 vG[4];
#pragma unroll
    for (int G = 0; G < 4; ++G) {
      int y = phg[G] + ky, xx = pwg[G] + kx;
      bool ok = ((unsigned)y < HH) && ((unsigned)xx < WW);
      int pos = ok ? (y * WW + xx) : 0;
      uint4 v = *(const uint4*)(x2nb + ((size_t)pos << 7) + l15 * 8);
      vG[G] = ok ? v : make_uint4(0u, 0u, 0u, 0u);
    }
#pragma unroll
    for (int j = 0; j < 2; ++j) {          // stage 32 oc rows x 64 dw
      int cc = t + 256 * j;
      int row = cc >> 4, c16 = cc & 15;
      *(uint4*)&bwA[row * 68 + c16 * 4] =
          *(const uint4*)(wt2b + (size_t)row * KTOT + tap * 128 + c16 * 8);
    }
#pragma unroll
    for (int G = 0; G < 4; ++G)
      *(uint4*)&val[w * 16 + G * 4 + quad][l15 * 8] = vG[G];
    __syncthreads();
#pragma unroll
    for (int ks = 0; ks < 4; ++ks) {
      f16x8 af = *(const f16x8*)&val[w * 16 + l15][ks * 32 + quad * 8];
      f16x8 b0 = *(const f16x8*)&bwA[(size_t)l15 * 68 + ks * 16 + quad * 4];
      f16x8 b1 = *(const f16x8*)&bwA[(size_t)(l15 + 16) * 68 + ks * 16 + quad * 4];
      oa0 = __builtin_amdgcn_mfma_f32_16x16x32_f16(af, b0, oa0, 0, 0, 0);
      oa1 = __builtin_amdgcn_mfma_f32_16x16x32_f16(af, b1, oa1, 0, 0, 0);
    }
    __syncthreads();
  }
  // dump om (+bias) into val-alias: col=px-in-block, row=oc.
#pragma unroll
  for (int nt = 0; nt < 2; ++nt) {
    f32x4 a = nt ? oa1 : oa0;
    int oc = nt * 16 + l15;
    float bia = bias32[oc];
#pragma unroll
    for (int r = 0; r < 4; ++r)
      om[oc * 68 + w * 16 + quad * 4 + r] = a[r] + bia;
  }
  __syncthreads();

  // ===== phase 2: bilinear params -> sidxw =====
  for (int e = t; e < KK * 64; e += 256) {
    int tap = e >> 6, pp = e & 63;
    int gp2 = pblk + pp;
    int h = gp2 / WW, ww_ = gp2 % WW;
    float dy = om[2 * tap * 68 + pp], dx = om[(2 * tap + 1) * 68 + pp];
    float mr = om[(18 + tap) * 68 + pp];
    float m = 1.f / (1.f + __expf(-mr));
    float py  = (float)(h + tap / 3 - 1) + dy;
    float pxx = (float)(ww_ + tap % 3 - 1) + dx;
    float y0f = floorf(py), x0f = floorf(pxx);
    int y0 = (int)y0f, x0 = (int)x0f;
    float ly = py - y0f, lx = pxx - x0f;
    int y1 = y0 + 1, x1 = x0 + 1;
    bool vy0 = (unsigned)y0 < HH, vy1 = (unsigned)y1 < HH;
    bool vx0 = (unsigned)x0 < WW, vx1 = (unsigned)x1 < WW;
    int cy0 = min(max(y0, 0), HH - 1), cy1 = min(max(y1, 0), HH - 1);
    int cx0 = min(max(x0, 0), WW - 1), cx1 = min(max(x1, 0), WW - 1);
    unsigned i00 = cy0 * WW + cx0, i01 = cy0 * WW + cx1;
    unsigned i10 = cy1 * WW + cx0, i11 = cy1 * WW + cx1;
    float w00 = (vy0 && vx0) ? m * (1.f - ly) * (1.f - lx) : 0.f;
    float w01 = (vy0 && vx1) ? m * (1.f - ly) * lx         : 0.f;
    float w10 = (vy1 && vx0) ? m * ly * (1.f - lx)         : 0.f;
    float w11 = (vy1 && vx1) ? m * ly * lx                 : 0.f;
    sidxw[(tap * 4 + 0) * 64 + pp] = i00 | ((unsigned)f2h(w00) << 16);
    sidxw[(tap * 4 + 1) * 64 + pp] = i01 | ((unsigned)f2h(w01) << 16);
    sidxw[(tap * 4 + 2) * 64 + pp] = i10 | ((unsigned)f2h(w10) << 16);
    sidxw[(tap * 4 + 3) * 64 + pp] = i11 | ((unsigned)f2h(w11) << 16);
  }
  __syncthreads();                          // om dead after this point

  // ===== phase 3: deformable GEMM, 2-barrier double-buffered =====
  // acc[h*4 + m*2 + ntl]: oc = h*64 + nw*32 + ntl*16 + l15,
  //                       px = mw*32 + m*16 + quad*4 + reg
  f32x4 acc[8];
#pragma unroll
  for (int nt = 0; nt < 8; ++nt) acc[nt] = (f32x4){0.f, 0.f, 0.f, 0.f};
  const unsigned short* xnb = xn + ((size_t)b * HWSZ) * 128;

  // helpers as lambdas (plain code, no asm)
  auto gatherT = [&](int tap, unsigned sw[4][4], uint4 v[4][4]) {
#pragma unroll
    for (int cr = 0; cr < 4; ++cr)
#pragma unroll
      for (int G = 0; G < 4; ++G)
        sw[cr][G] = sidxw[(tap * 4 + cr) * 64 + w * 16 + G * 4 + quad];
#pragma unroll
    for (int G = 0; G < 4; ++G)
#pragma unroll
      for (int cr = 0; cr < 4; ++cr)
        v[cr][G] = *(const uint4*)(xnb + ((size_t)(sw[cr][G] & 0xffffu) << 7) + l15 * 8);
  };
  auto combineT = [&](unsigned sw[4][4], uint4 v[4][4]) {
#pragma unroll
    for (int G = 0; G < 4; ++G) {
      h2 f[4];
#pragma unroll
      for (int j = 0; j < 4; ++j) f[j] = (h2){(_Float16)0.f, (_Float16)0.f};
#pragma unroll
      for (int cr = 0; cr < 4; ++cr) {
        _Float16 wh =
            __builtin_bit_cast(_Float16, (unsigned short)(sw[cr][G] >> 16));
        h2 wpk = {wh, wh};
        const h2* a = (const h2*)&v[cr][G];
#pragma unroll
        for (int j = 0; j < 4; ++j)
          f[j] += wpk * a[j];                    // v_pk_fma_f16
      }
      *(uint4*)&val[w * 16 + G * 4 + quad][l15 * 8] =
          make_uint4(__builtin_bit_cast(unsigned, f[0]),
                     __builtin_bit_cast(unsigned, f[1]),
                     __builtin_bit_cast(unsigned, f[2]),
                     __builtin_bit_cast(unsigned, f[3]));
    }
  };
  auto stageHalf = [&](unsigned* buf, int tap, int half) {
#pragma unroll
    for (int j = 0; j < 4; ++j) {
      int cc = t + 256 * j;
      int row = cc >> 4, c16 = cc & 15;
      *(uint4*)&buf[row * 68 + c16 * 4] =
          *(const uint4*)(wtb + (size_t)(half * 64 + row) * KTOT + tap * 128 + c16 * 8);
    }
  };

  // prologue: tap 0 A-tile + bwA
  {
    unsigned sw[4][4]; uint4 v[4][4];
    gatherT(0, sw, v);
    combineT(sw, v);
    stageHalf(bwA, 0, 0);
  }
  __syncthreads();                               // B1(0)

  for (int tap = 0; tap < KK; ++tap) {
    // ---- W1: af-read | mfma0 @ bwA | stage1 -> bwB ----
    f16x8 af[2][4];
#pragma unroll
    for (int m = 0; m < 2; ++m)
#pragma unroll
      for (int ks = 0; ks < 4; ++ks)
        af[m][ks] =
            *(const f16x8*)&val[mw * 32 + m * 16 + l15][ks * 32 + quad * 8];
    stageHalf(bwB, tap, 1);
#pragma unroll
    for (int m = 0; m < 2; ++m)
#pragma unroll
      for (int ntl = 0; ntl < 2; ++ntl)
#pragma unroll
        for (int ks = 0; ks < 4; ++ks) {
          f16x8 bb = *(const f16x8*)&bwA[(size_t)(nw * 32 + ntl * 16 + l15) * 68 +
                                         ks * 16 + quad * 4];
          acc[m * 2 + ntl] =
              __builtin_amdgcn_mfma_f32_16x16x32_f16(af[m][ks], bb,
                                                     acc[m * 2 + ntl], 0, 0, 0);
        }
    __syncthreads();                             // B2(tap)
    // ---- W2: gather(t+1) | mfma1 @ bwB | combine(t+1)+val-write | stage0 ----
    unsigned sw[4][4]; uint4 v[4][4];
    if (tap + 1 < KK) gatherT(tap + 1, sw, v);   // issue loads first
#pragma unroll
    for (int m = 0; m < 2; ++m)
#pragma unroll
      for (int ntl = 0; ntl < 2; ++ntl)
#pragma unroll
        for (int ks = 0; ks < 4; ++ks) {
          f16x8 bb = *(const f16x8*)&bwB[(size_t)(nw * 32 + ntl * 16 + l15) * 68 +
                                         ks * 16 + quad * 4];
          acc[4 + m * 2 + ntl] =
              __builtin_amdgcn_mfma_f32_16x16x32_f16(af[m][ks], bb,
                                                     acc[4 + m * 2 + ntl], 0, 0, 0);
        }
    if (tap + 1 < KK) {
      combineT(sw, v);
      stageHalf(bwA, tap + 1, 0);
      __syncthreads();                           // B1(tap+1)
    }
  }

  // ===== phase 4: direct epilogue (reg = 4 consecutive px -> float4 store) ===
#pragma unroll
  for (int h = 0; h < 2; ++h)
#pragma unroll
    for (int m = 0; m < 2; ++m)
#pragma unroll
      for (int ntl = 0; ntl < 2; ++ntl) {
        int oc = h * 64 + nw * 32 + ntl * 16 + l15;
        f32x4 a = acc[h * 4 + m * 2 + ntl];
        float db = defb[oc];
        float4 vv = make_float4(a[0] + db, a[1] + db, a[2] + db, a[3] + db);
        *(float4*)&out[((size_t)b * OUTC + oc) * HWSZ + pblk + mw * 32 +
                       m * 16 + quad * 4] = vv;
      }
}

extern "C" void kernel_launch(void* const* d_in, const int* in_sizes, int n_in,
                              void* d_out, int out_size, void* d_ws, size_t ws_size,
                              hipStream_t stream) {
  const float* x     = (const float*)d_in[0];
  const float* x2    = (const float*)d_in[1];
  const float* offw  = (const float*)d_in[2];
  const float* offb  = (const float*)d_in[3];
  const float* maskw = (const float*)d_in[4];
  const float* maskb = (const float*)d_in[5];
  const float* defw  = (const float*)d_in[6];
  const float* defb  = (const float*)d_in[7];
  float* out = (float*)d_out;

  hipLaunchKernelGGL(prep_all, dim3(1873), dim3(256), 0, stream,
                     x, x2, offw, maskw, defw, offb, maskb, d_ws);
  hipLaunchKernelGGL(fused, dim3(576), dim3(256), 0, stream, defb, d_ws, out);
}

// Round 12
// 139.390 us; speedup vs baseline: 1.1022x; 1.1022x over previous
//
#include <hip/hip_runtime.h>

// DeformConv fused fp16: quarter-double-buffered phase 3 at 44KB LDS.
// 4 windows/tap, each mixing MFMA + stage + gather/combine; 3 blocks/CU kept.
// B=4, C=128, H=W=96, O=128, 3x3 s1 p1 d1, G=1.
#define CIN   128
#define HH    96
#define WW    96
#define OUTC  128
#define HWSZ  9216
#define KK    9
#define KTOT  1152        // k' = tap*128 + c (tap-major)

typedef _Float16 f16x8 __attribute__((ext_vector_type(8)));
typedef _Float16 h2    __attribute__((ext_vector_type(2)));
typedef float    f32x4 __attribute__((ext_vector_type(4)));

__device__ __forceinline__ unsigned short f2h(float f) {
  _Float16 h = (_Float16)f;                      // v_cvt_f16_f32 (RNE)
  return __builtin_bit_cast(unsigned short, h);
}
// pack two floats to f16x2 (RTZ) : 1 VALU
__device__ __forceinline__ unsigned pack_h(float v0, float v1) {
  auto r = __builtin_amdgcn_cvt_pkrtz(v0, v1);   // lo = v0, hi = v1
  return __builtin_bit_cast(unsigned, r);
}

// ws layout (u16 offsets):
//   wtb   f16[128][1152] @ 0         (k' = tap*128+c)
//   wt2b  f16[32][1152]  @ 147456    (oc 0-17 offset, 18-26 mask, 27-31 zero)
//   bias32 f32[32]       @ 184320
//   xn    f16[4][9216][128] @ 184384 (NHWC)
//   x2n   f16[4][9216][128] @ 184384+4718592
#define WT2B_O 147456
#define BIAS_O 184320
#define XN_O   184384
#define X2N_O  (184384 + 4718592)

// Combined prep: blocks [0,1152) = NCHW->NHWC f16 transpose of x/x2
// (float4 loads: 4 px/lane, 16 c-rows/pass; uint4 stores);
// blocks [1152,1873) = weight reorder/cast.
__global__ __launch_bounds__(256) void prep_all(
    const float* __restrict__ x, const float* __restrict__ x2,
    const float* __restrict__ offw, const float* __restrict__ maskw,
    const float* __restrict__ defw, const float* __restrict__ offb,
    const float* __restrict__ maskb, void* __restrict__ wsv) {
  int bid = blockIdx.x;
  int t = threadIdx.x;
  if (bid < 1152) {
    // u16 tile[64 px][136] (word stride 68): word (c>>1) holds {c, c+1}
    __shared__ unsigned short tile[64][136];
    int tsel = bid / 576;
    int rem = bid - tsel * 576;
    int b = rem / 144;
    int hw0 = (rem % 144) * 64;
    const float* src = tsel ? x2 : x;
    unsigned short* dst = (unsigned short*)wsv + (tsel ? X2N_O : XN_O);
    unsigned* tw = (unsigned*)&tile[0][0];
    int c2  = t & 15;        // channel-pair index within pass
    int px4 = t >> 4;        // 0..15 -> px = px4*4..+3
#pragma unroll
    for (int pass = 0; pass < 4; ++pass) {
      int c = pass * 32 + c2 * 2;
      const float* r0 = src + ((size_t)(b * CIN + c)) * HWSZ + hw0 + px4 * 4;
      float4 f0 = *(const float4*)r0;          // 4 px of channel c
      float4 f1 = *(const float4*)(r0 + HWSZ); // 4 px of channel c+1
      int wb = pass * 16 + c2;                 // = c>>1
      tw[(px4 * 4 + 0) * 68 + wb] = pack_h(f0.x, f1.x);
      tw[(px4 * 4 + 1) * 68 + wb] = pack_h(f0.y, f1.y);
      tw[(px4 * 4 + 2) * 68 + wb] = pack_h(f0.z, f1.z);
      tw[(px4 * 4 + 3) * 68 + wb] = pack_h(f0.w, f1.w);
    }
    __syncthreads();
    unsigned* drow = (unsigned*)(dst + ((size_t)(b * HWSZ + hw0)) * 128);
    int w4 = t & 15, pxr = t >> 4;
#pragma unroll
    for (int pass = 0; pass < 4; ++pass) {
      int px = pass * 16 + pxr;
      uint4 v = *(const uint4*)&tw[px * 68 + w4 * 4];
      *(uint4*)&drow[(size_t)px * 64 + w4 * 4] = v;
    }
    return;
  }
  unsigned short* wtb  = (unsigned short*)wsv;
  unsigned short* wt2b = wtb + WT2B_O;
  float* bias32 = (float*)(wtb + BIAS_O);
  int idx = (bid - 1152) * 256 + t;
  if (idx < OUTC * KTOT) {
    int o = idx / KTOT, r = idx - o * KTOT;
    int c = r / KK, tap = r - c * KK;
    wtb[o * KTOT + tap * 128 + c] = f2h(defw[idx]);
  } else if (idx < OUTC * KTOT + 32 * KTOT) {
    int j = idx - OUTC * KTOT;
    int oc = j / KTOT, r = j - oc * KTOT;
    int c = r / KK, tap = r - c * KK;
    float v = 0.f;
    if (oc < 18)      v = offw[j];
    else if (oc < 27) v = maskw[j - 18 * KTOT];
    wt2b[oc * KTOT + tap * 128 + c] = f2h(v);
  } else if (idx < OUTC * KTOT + 32 * KTOT + 32) {
    int j = idx - OUTC * KTOT - 32 * KTOT;
    float v = 0.f;
    if (j < 18) v = offb[j]; else if (j < 27) v = maskb[j - 18];
    bias32[j] = v;
  }
}

// Fused: block = 64-px strip.
// Gather roles: wave w gathers px strip w*16..+15, lanes (quad = px-in-group,
// l15 = channel octet) -> full 256B row reads; combine via v_pk_fma_f16 -> val.
// Phase 3: B staged in 32-oc-row QUARTERS, double-buffered bwA/bwB (8.7KB ea).
// Wave grid: mw = px half (32px), nw = 16-oc slice of current quarter.
// Per tap, 4 windows (W1..W4), each = mfma(q) + stage(q+1) + gather/combine
// slice of tap+1. All val/bwA/bwB hazards one-barrier-separated (audited).
// om aliases val; direct f32x4 epilogue. LDS 44KB -> 3 blocks/CU.
__global__ __launch_bounds__(256, 3) void fused(
    const float* __restrict__ defb, const void* __restrict__ wsv,
    float* __restrict__ out) {
  const unsigned short* wtb  = (const unsigned short*)wsv;
  const unsigned short* wt2b = wtb + WT2B_O;
  const float* bias32 = (const float*)(wtb + BIAS_O);
  const unsigned short* xn  = wtb + XN_O;
  const unsigned short* x2n = wtb + X2N_O;

  __shared__ unsigned bwA[32 * 68];        // 8.7 KB: B quarter buffer A
  __shared__ unsigned bwB[32 * 68];        // 8.7 KB: B quarter buffer B
  __shared__ unsigned short val[64][136];  // 17.4 KB: A tile (f16), pad 136
  __shared__ unsigned sidxw[KK * 4 * 64];  // 9.2 KB: [(tap*4+cr)*64+px] idx|w<<16
  float* om = (float*)&val[0][0];          // alias: om[oc*68+pp], 8.7 KB

  int t = threadIdx.x;
  int w = t >> 6;
  int mw = w & 1, nw = w >> 1;             // phase-3 wave grid
  int l15 = t & 15, quad = (t >> 4) & 3;
  int rb = blockIdx.x;
  int bid = (rb & 7) * 72 + (rb >> 3);     // XCD swizzle
  int b = bid / 144;
  int pblk = (bid % 144) * 64;

  // gather-role pixels: px = 16w + G*4 + quad
  int phg[4], pwg[4];
#pragma unroll
  for (int G = 0; G < 4; ++G) {
    int p = pblk + w * 16 + G * 4 + quad;
    phg[G] = p / WW;
    pwg[G] = p - phg[G] * WW;
  }

  // ===== phase 1: offset/mask GEMM (uses bwA as 32-row stage) =====
  f32x4 oa0 = {0.f, 0.f, 0.f, 0.f};
  f32x4 oa1 = {0.f, 0.f, 0.f, 0.f};
  const unsigned short* x2nb = x2n + ((size_t)b * HWSZ) * 128;
  for (int tap = 0; tap < KK; ++tap) {
    int ky = tap / 3 - 1, kx = tap % 3 - 1;
    uint4 vG[4];
#pragma unroll
    for (int G = 0; G < 4; ++G) {
      int y = phg[G] + ky, xx = pwg[G] + kx;
      bool ok = ((unsigned)y < HH) && ((unsigned)xx < WW);
      int pos = ok ? (y * WW + xx) : 0;
      uint4 v = *(const uint4*)(x2nb + ((size_t)pos << 7) + l15 * 8);
      vG[G] = ok ? v : make_uint4(0u, 0u, 0u, 0u);
    }
#pragma unroll
    for (int j = 0; j < 2; ++j) {          // stage 32 oc rows x 64 dw
      int cc = t + 256 * j;
      int row = cc >> 4, c16 = cc & 15;
      *(uint4*)&bwA[row * 68 + c16 * 4] =
          *(const uint4*)(wt2b + (size_t)row * KTOT + tap * 128 + c16 * 8);
    }
#pragma unroll
    for (int G = 0; G < 4; ++G)
      *(uint4*)&val[w * 16 + G * 4 + quad][l15 * 8] = vG[G];
    __syncthreads();
#pragma unroll
    for (int ks = 0; ks < 4; ++ks) {
      f16x8 af = *(const f16x8*)&val[w * 16 + l15][ks * 32 + quad * 8];
      f16x8 b0 = *(const f16x8*)&bwA[(size_t)l15 * 68 + ks * 16 + quad * 4];
      f16x8 b1 = *(const f16x8*)&bwA[(size_t)(l15 + 16) * 68 + ks * 16 + quad * 4];
      oa0 = __builtin_amdgcn_mfma_f32_16x16x32_f16(af, b0, oa0, 0, 0, 0);
      oa1 = __builtin_amdgcn_mfma_f32_16x16x32_f16(af, b1, oa1, 0, 0, 0);
    }
    __syncthreads();
  }
  // dump om (+bias) into val-alias: col=px-in-block, row=oc.
#pragma unroll
  for (int nt = 0; nt < 2; ++nt) {
    f32x4 a = nt ? oa1 : oa0;
    int oc = nt * 16 + l15;
    float bia = bias32[oc];
#pragma unroll
    for (int r = 0; r < 4; ++r)
      om[oc * 68 + w * 16 + quad * 4 + r] = a[r] + bia;
  }
  __syncthreads();

  // ===== phase 2: bilinear params -> sidxw =====
  for (int e = t; e < KK * 64; e += 256) {
    int tap = e >> 6, pp = e & 63;
    int gp2 = pblk + pp;
    int h = gp2 / WW, ww_ = gp2 % WW;
    float dy = om[2 * tap * 68 + pp], dx = om[(2 * tap + 1) * 68 + pp];
    float mr = om[(18 + tap) * 68 + pp];
    float m = 1.f / (1.f + __expf(-mr));
    float py  = (float)(h + tap / 3 - 1) + dy;
    float pxx = (float)(ww_ + tap % 3 - 1) + dx;
    float y0f = floorf(py), x0f = floorf(pxx);
    int y0 = (int)y0f, x0 = (int)x0f;
    float ly = py - y0f, lx = pxx - x0f;
    int y1 = y0 + 1, x1 = x0 + 1;
    bool vy0 = (unsigned)y0 < HH, vy1 = (unsigned)y1 < HH;
    bool vx0 = (unsigned)x0 < WW, vx1 = (unsigned)x1 < WW;
    int cy0 = min(max(y0, 0), HH - 1), cy1 = min(max(y1, 0), HH - 1);
    int cx0 = min(max(x0, 0), WW - 1), cx1 = min(max(x1, 0), WW - 1);
    unsigned i00 = cy0 * WW + cx0, i01 = cy0 * WW + cx1;
    unsigned i10 = cy1 * WW + cx0, i11 = cy1 * WW + cx1;
    float w00 = (vy0 && vx0) ? m * (1.f - ly) * (1.f - lx) : 0.f;
    float w01 = (vy0 && vx1) ? m * (1.f - ly) * lx         : 0.f;
    float w10 = (vy1 && vx0) ? m * ly * (1.f - lx)         : 0.f;
    float w11 = (vy1 && vx1) ? m * ly * lx                 : 0.f;
    sidxw[(tap * 4 + 0) * 64 + pp] = i00 | ((unsigned)f2h(w00) << 16);
    sidxw[(tap * 4 + 1) * 64 + pp] = i01 | ((unsigned)f2h(w01) << 16);
    sidxw[(tap * 4 + 2) * 64 + pp] = i10 | ((unsigned)f2h(w10) << 16);
    sidxw[(tap * 4 + 3) * 64 + pp] = i11 | ((unsigned)f2h(w11) << 16);
  }
  __syncthreads();                          // om dead after this point

  // ===== phase 3: deformable GEMM, quarter-double-buffered =====
  // acc[q][m]: oc = q*32 + nw*16 + l15, px = mw*32 + m*16 + quad*4 + reg
  f32x4 acc[4][2];
#pragma unroll
  for (int q = 0; q < 4; ++q)
#pragma unroll
    for (int m = 0; m < 2; ++m) acc[q][m] = (f32x4){0.f, 0.f, 0.f, 0.f};
  const unsigned short* xnb = xn + ((size_t)b * HWSZ) * 128;

  // half-batch gather (G = 2h, 2h+1): 8 loads, 32 VGPR of data
  auto gatherH = [&](int tap, int h, unsigned sw[2], uint4 v[2][4]) {
#pragma unroll
    for (int gi = 0; gi < 2; ++gi) {
      int G = 2 * h + gi;
      // pack 4 corner words into per-G fetches
#pragma unroll
      for (int cr = 0; cr < 4; ++cr) {
        unsigned s = sidxw[(tap * 4 + cr) * 64 + w * 16 + G * 4 + quad];
        if (cr == 0) sw[gi] = 0;           // sw unused per-corner; keep idx/w inline
        v[gi][cr] = *(const uint4*)(xnb + ((size_t)(s & 0xffffu) << 7) + l15 * 8);
        // stash weight in high bits of an aux array via sw? use separate array:
        // handled below by re-reading sidxw in combineH (LDS read is cheap).
      }
    }
  };
  auto combineH = [&](int tap, int h, uint4 v[2][4]) {
#pragma unroll
    for (int gi = 0; gi < 2; ++gi) {
      int G = 2 * h + gi;
      h2 f[4];
#pragma unroll
      for (int j = 0; j < 4; ++j) f[j] = (h2){(_Float16)0.f, (_Float16)0.f};
#pragma unroll
      for (int cr = 0; cr < 4; ++cr) {
        unsigned s = sidxw[(tap * 4 + cr) * 64 + w * 16 + G * 4 + quad];
        _Float16 wh = __builtin_bit_cast(_Float16, (unsigned short)(s >> 16));
        h2 wpk = {wh, wh};
        const h2* a = (const h2*)&v[gi][cr];
#pragma unroll
        for (int j = 0; j < 4; ++j)
          f[j] += wpk * a[j];                    // v_pk_fma_f16
      }
      *(uint4*)&val[w * 16 + G * 4 + quad][l15 * 8] =
          make_uint4(__builtin_bit_cast(unsigned, f[0]),
                     __builtin_bit_cast(unsigned, f[1]),
                     __builtin_bit_cast(unsigned, f[2]),
                     __builtin_bit_cast(unsigned, f[3]));
    }
  };
  auto stageQ = [&](unsigned* buf, int tap, int q) {
#pragma unroll
    for (int j = 0; j < 2; ++j) {
      int cc = t + 256 * j;
      int row = cc >> 4, c16 = cc & 15;
      *(uint4*)&buf[row * 68 + c16 * 4] =
          *(const uint4*)(wtb + (size_t)(q * 32 + row) * KTOT + tap * 128 + c16 * 8);
    }
  };
  auto mfmaQ = [&](const unsigned* buf, f32x4* aq, f16x8 af[2][4]) {
#pragma unroll
    for (int ks = 0; ks < 4; ++ks) {
      f16x8 bb = *(const f16x8*)&buf[(size_t)(nw * 16 + l15) * 68 +
                                     ks * 16 + quad * 4];
      aq[0] = __builtin_amdgcn_mfma_f32_16x16x32_f16(af[0][ks], bb, aq[0], 0, 0, 0);
      aq[1] = __builtin_amdgcn_mfma_f32_16x16x32_f16(af[1][ks], bb, aq[1], 0, 0, 0);
    }
  };

  // prologue: val(tap 0) + bwA q0
  {
    unsigned swd[2]; uint4 v0[2][4], v1[2][4];
    gatherH(0, 0, swd, v0);
    gatherH(0, 1, swd, v1);
    combineH(0, 0, v0);
    combineH(0, 1, v1);
    stageQ(bwA, 0, 0);
  }
  __syncthreads();

  for (int tap = 0; tap < KK; ++tap) {
    bool more = (tap + 1 < KK);
    unsigned swd[2]; uint4 v01[2][4], v23[2][4];
    // ---- W1: af-read | mfma q0 @ bwA | stage q1 -> bwB ----
    f16x8 af[2][4];
#pragma unroll
    for (int m = 0; m < 2; ++m)
#pragma unroll
      for (int ks = 0; ks < 4; ++ks)
        af[m][ks] =
            *(const f16x8*)&val[mw * 32 + m * 16 + l15][ks * 32 + quad * 8];
    stageQ(bwB, tap, 1);
    mfmaQ(bwA, acc[0], af);
    __syncthreads();
    // ---- W2: gather G0-G1(t+1) | mfma q1 @ bwB | stage q2 -> bwA ----
    if (more) gatherH(tap + 1, 0, swd, v01);
    stageQ(bwA, tap, 2);
    mfmaQ(bwB, acc[1], af);
    __syncthreads();
    // ---- W3: combine G0-G1 | gather G2-G3(t+1) | mfma q2 @ bwA | stage q3 ----
    if (more) {
      combineH(tap + 1, 0, v01);
      gatherH(tap + 1, 1, swd, v23);
    }
    stageQ(bwB, tap, 3);
    mfmaQ(bwA, acc[2], af);
    __syncthreads();
    // ---- W4: combine G2-G3 | mfma q3 @ bwB | stage q0(t+1) -> bwA ----
    if (more) {
      combineH(tap + 1, 1, v23);
      stageQ(bwA, tap + 1, 0);
    }
    mfmaQ(bwB, acc[3], af);
    if (more) __syncthreads();
  }

  // ===== phase 4: direct epilogue (reg = 4 consecutive px -> float4 store) ===
#pragma unroll
  for (int q = 0; q < 4; ++q)
#pragma unroll
    for (int m = 0; m < 2; ++m) {
      int oc = q * 32 + nw * 16 + l15;
      f32x4 a = acc[q][m];
      float db = defb[oc];
      float4 vv = make_float4(a[0] + db, a[1] + db, a[2] + db, a[3] + db);
      *(float4*)&out[((size_t)b * OUTC + oc) * HWSZ + pblk + mw * 32 +
                     m * 16 + quad * 4] = vv;
    }
}

extern "C" void kernel_launch(void* const* d_in, const int* in_sizes, int n_in,
                              void* d_out, int out_size, void* d_ws, size_t ws_size,
                              hipStream_t stream) {
  const float* x     = (const float*)d_in[0];
  const float* x2    = (const float*)d_in[1];
  const float* offw  = (const float*)d_in[2];
  const float* offb  = (const float*)d_in[3];
  const float* maskw = (const float*)d_in[4];
  const float* maskb = (const float*)d_in[5];
  const float* defw  = (const float*)d_in[6];
  const float* defb  = (const float*)d_in[7];
  float* out = (float*)d_out;

  hipLaunchKernelGGL(prep_all, dim3(1873), dim3(256), 0, stream,
                     x, x2, offw, maskw, defw, offb, maskb, d_ws);
  hipLaunchKernelGGL(fused, dim3(576), dim3(256), 0, stream, defb, d_ws, out);
}

// Round 13
// 138.497 us; speedup vs baseline: 1.1093x; 1.0065x over previous
//
#include <hip/hip_runtime.h>

// DeformConv fused fp16: quarter-double-buffered phase 3 (r12) +
// pipelined phase 1 (1 barrier/tap, wave-private val, dbuf B-stage).
// B=4, C=128, H=W=96, O=128, 3x3 s1 p1 d1, G=1.
#define CIN   128
#define HH    96
#define WW    96
#define OUTC  128
#define HWSZ  9216
#define KK    9
#define KTOT  1152        // k' = tap*128 + c (tap-major)

typedef _Float16 f16x8 __attribute__((ext_vector_type(8)));
typedef _Float16 h2    __attribute__((ext_vector_type(2)));
typedef float    f32x4 __attribute__((ext_vector_type(4)));

__device__ __forceinline__ unsigned short f2h(float f) {
  _Float16 h = (_Float16)f;                      // v_cvt_f16_f32 (RNE)
  return __builtin_bit_cast(unsigned short, h);
}
// pack two floats to f16x2 (RTZ) : 1 VALU
__device__ __forceinline__ unsigned pack_h(float v0, float v1) {
  auto r = __builtin_amdgcn_cvt_pkrtz(v0, v1);   // lo = v0, hi = v1
  return __builtin_bit_cast(unsigned, r);
}

// ws layout (u16 offsets):
//   wtb   f16[128][1152] @ 0         (k' = tap*128+c)
//   wt2b  f16[32][1152]  @ 147456    (oc 0-17 offset, 18-26 mask, 27-31 zero)
//   bias32 f32[32]       @ 184320
//   xn    f16[4][9216][128] @ 184384 (NHWC)
//   x2n   f16[4][9216][128] @ 184384+4718592
#define WT2B_O 147456
#define BIAS_O 184320
#define XN_O   184384
#define X2N_O  (184384 + 4718592)

// Combined prep: blocks [0,1152) = NCHW->NHWC f16 transpose of x/x2
// (float4 loads: 4 px/lane, 16 c-rows/pass; uint4 stores);
// blocks [1152,1873) = weight reorder/cast.
__global__ __launch_bounds__(256) void prep_all(
    const float* __restrict__ x, const float* __restrict__ x2,
    const float* __restrict__ offw, const float* __restrict__ maskw,
    const float* __restrict__ defw, const float* __restrict__ offb,
    const float* __restrict__ maskb, void* __restrict__ wsv) {
  int bid = blockIdx.x;
  int t = threadIdx.x;
  if (bid < 1152) {
    // u16 tile[64 px][136] (word stride 68): word (c>>1) holds {c, c+1}
    __shared__ unsigned short tile[64][136];
    int tsel = bid / 576;
    int rem = bid - tsel * 576;
    int b = rem / 144;
    int hw0 = (rem % 144) * 64;
    const float* src = tsel ? x2 : x;
    unsigned short* dst = (unsigned short*)wsv + (tsel ? X2N_O : XN_O);
    unsigned* tw = (unsigned*)&tile[0][0];
    int c2  = t & 15;        // channel-pair index within pass
    int px4 = t >> 4;        // 0..15 -> px = px4*4..+3
#pragma unroll
    for (int pass = 0; pass < 4; ++pass) {
      int c = pass * 32 + c2 * 2;
      const float* r0 = src + ((size_t)(b * CIN + c)) * HWSZ + hw0 + px4 * 4;
      float4 f0 = *(const float4*)r0;          // 4 px of channel c
      float4 f1 = *(const float4*)(r0 + HWSZ); // 4 px of channel c+1
      int wb = pass * 16 + c2;                 // = c>>1
      tw[(px4 * 4 + 0) * 68 + wb] = pack_h(f0.x, f1.x);
      tw[(px4 * 4 + 1) * 68 + wb] = pack_h(f0.y, f1.y);
      tw[(px4 * 4 + 2) * 68 + wb] = pack_h(f0.z, f1.z);
      tw[(px4 * 4 + 3) * 68 + wb] = pack_h(f0.w, f1.w);
    }
    __syncthreads();
    unsigned* drow = (unsigned*)(dst + ((size_t)(b * HWSZ + hw0)) * 128);
    int w4 = t & 15, pxr = t >> 4;
#pragma unroll
    for (int pass = 0; pass < 4; ++pass) {
      int px = pass * 16 + pxr;
      uint4 v = *(const uint4*)&tw[px * 68 + w4 * 4];
      *(uint4*)&drow[(size_t)px * 64 + w4 * 4] = v;
    }
    return;
  }
  unsigned short* wtb  = (unsigned short*)wsv;
  unsigned short* wt2b = wtb + WT2B_O;
  float* bias32 = (float*)(wtb + BIAS_O);
  int idx = (bid - 1152) * 256 + t;
  if (idx < OUTC * KTOT) {
    int o = idx / KTOT, r = idx - o * KTOT;
    int c = r / KK, tap = r - c * KK;
    wtb[o * KTOT + tap * 128 + c] = f2h(defw[idx]);
  } else if (idx < OUTC * KTOT + 32 * KTOT) {
    int j = idx - OUTC * KTOT;
    int oc = j / KTOT, r = j - oc * KTOT;
    int c = r / KK, tap = r - c * KK;
    float v = 0.f;
    if (oc < 18)      v = offw[j];
    else if (oc < 27) v = maskw[j - 18 * KTOT];
    wt2b[oc * KTOT + tap * 128 + c] = f2h(v);
  } else if (idx < OUTC * KTOT + 32 * KTOT + 32) {
    int j = idx - OUTC * KTOT - 32 * KTOT;
    float v = 0.f;
    if (j < 18) v = offb[j]; else if (j < 27) v = maskb[j - 18];
    bias32[j] = v;
  }
}

// Fused: block = 64-px strip.
// Gather roles: wave w gathers px strip w*16..+15, lanes (quad = px-in-group,
// l15 = channel octet) -> full 256B row reads; combine via v_pk_fma_f16 -> val.
// Phase 1: pipelined, 1 barrier/tap. val is WAVE-PRIVATE in phase 1 (wave w
// writes rows w*16..+15, af reads row w*16+l15; same-wave LDS ops are
// in-order) -> no barrier for val. B stage (32 rows) double-buffered bwA/bwB;
// the single barrier separates nxt-write from next-window read and drains
// cur reads before the t+2 overwrite.
// Phase 3: B staged in 32-oc-row QUARTERS, double-buffered bwA/bwB (8.7KB ea).
// Wave grid: mw = px half (32px), nw = 16-oc slice of current quarter.
// Per tap, 4 windows (W1..W4), each = mfma(q) + stage(q+1) + gather/combine
// slice of tap+1. All val/bwA/bwB hazards one-barrier-separated (audited).
// om aliases val; direct f32x4 epilogue. LDS 44KB -> 3 blocks/CU.
__global__ __launch_bounds__(256, 3) void fused(
    const float* __restrict__ defb, const void* __restrict__ wsv,
    float* __restrict__ out) {
  const unsigned short* wtb  = (const unsigned short*)wsv;
  const unsigned short* wt2b = wtb + WT2B_O;
  const float* bias32 = (const float*)(wtb + BIAS_O);
  const unsigned short* xn  = wtb + XN_O;
  const unsigned short* x2n = wtb + X2N_O;

  __shared__ unsigned bwA[32 * 68];        // 8.7 KB: B quarter buffer A
  __shared__ unsigned bwB[32 * 68];        // 8.7 KB: B quarter buffer B
  __shared__ unsigned short val[64][136];  // 17.4 KB: A tile (f16), pad 136
  __shared__ unsigned sidxw[KK * 4 * 64];  // 9.2 KB: [(tap*4+cr)*64+px] idx|w<<16
  float* om = (float*)&val[0][0];          // alias: om[oc*68+pp], 8.7 KB

  int t = threadIdx.x;
  int w = t >> 6;
  int mw = w & 1, nw = w >> 1;             // phase-3 wave grid
  int l15 = t & 15, quad = (t >> 4) & 3;
  int rb = blockIdx.x;
  int bid = (rb & 7) * 72 + (rb >> 3);     // XCD swizzle
  int b = bid / 144;
  int pblk = (bid % 144) * 64;

  // gather-role pixels: px = 16w + G*4 + quad
  int phg[4], pwg[4];
#pragma unroll
  for (int G = 0; G < 4; ++G) {
    int p = pblk + w * 16 + G * 4 + quad;
    phg[G] = p / WW;
    pwg[G] = p - phg[G] * WW;
  }

  // ===== phase 1: offset/mask GEMM, pipelined (1 barrier/tap) =====
  f32x4 oa0 = {0.f, 0.f, 0.f, 0.f};
  f32x4 oa1 = {0.f, 0.f, 0.f, 0.f};
  const unsigned short* x2nb = x2n + ((size_t)b * HWSZ) * 128;
  auto gather1 = [&](int tap, uint4 vG[4]) {
    int ky = tap / 3 - 1, kx = tap % 3 - 1;
#pragma unroll
    for (int G = 0; G < 4; ++G) {
      int y = phg[G] + ky, xx = pwg[G] + kx;
      bool ok = ((unsigned)y < HH) && ((unsigned)xx < WW);
      int pos = ok ? (y * WW + xx) : 0;
      uint4 v = *(const uint4*)(x2nb + ((size_t)pos << 7) + l15 * 8);
      vG[G] = ok ? v : make_uint4(0u, 0u, 0u, 0u);
    }
  };
  auto stage1 = [&](unsigned* buf, int tap) {
#pragma unroll
    for (int j = 0; j < 2; ++j) {          // stage 32 oc rows x 64 dw
      int cc = t + 256 * j;
      int row = cc >> 4, c16 = cc & 15;
      *(uint4*)&buf[row * 68 + c16 * 4] =
          *(const uint4*)(wt2b + (size_t)row * KTOT + tap * 128 + c16 * 8);
    }
  };
  auto valw1 = [&](uint4 vG[4]) {
#pragma unroll
    for (int G = 0; G < 4; ++G)
      *(uint4*)&val[w * 16 + G * 4 + quad][l15 * 8] = vG[G];
  };
  {
    uint4 vG[4];
    gather1(0, vG);
    stage1(bwA, 0);
    valw1(vG);
  }
  __syncthreads();
  for (int tap = 0; tap < KK; ++tap) {
    unsigned* cur = (tap & 1) ? bwB : bwA;
    unsigned* nxt = (tap & 1) ? bwA : bwB;
    uint4 vN[4];
    bool more = (tap + 1 < KK);
    if (more) {
      gather1(tap + 1, vN);                // issue next-tap gathers first
      stage1(nxt, tap + 1);                // stage next-tap B half
    }
#pragma unroll
    for (int ks = 0; ks < 4; ++ks) {
      f16x8 af = *(const f16x8*)&val[w * 16 + l15][ks * 32 + quad * 8];
      f16x8 b0 = *(const f16x8*)&cur[(size_t)l15 * 68 + ks * 16 + quad * 4];
      f16x8 b1 = *(const f16x8*)&cur[(size_t)(l15 + 16) * 68 + ks * 16 + quad * 4];
      oa0 = __builtin_amdgcn_mfma_f32_16x16x32_f16(af, b0, oa0, 0, 0, 0);
      oa1 = __builtin_amdgcn_mfma_f32_16x16x32_f16(af, b1, oa1, 0, 0, 0);
    }
    if (more) valw1(vN);                   // own rows, after af reads (in-order)
    __syncthreads();
  }
  // dump om (+bias) into val-alias: col=px-in-block, row=oc.
#pragma unroll
  for (int nt = 0; nt < 2; ++nt) {
    f32x4 a = nt ? oa1 : oa0;
    int oc = nt * 16 + l15;
    float bia = bias32[oc];
#pragma unroll
    for (int r = 0; r < 4; ++r)
      om[oc * 68 + w * 16 + quad * 4 + r] = a[r] + bia;
  }
  __syncthreads();

  // ===== phase 2: bilinear params -> sidxw =====
  for (int e = t; e < KK * 64; e += 256) {
    int tap = e >> 6, pp = e & 63;
    int gp2 = pblk + pp;
    int h = gp2 / WW, ww_ = gp2 % WW;
    float dy = om[2 * tap * 68 + pp], dx = om[(2 * tap + 1) * 68 + pp];
    float mr = om[(18 + tap) * 68 + pp];
    float m = 1.f / (1.f + __expf(-mr));
    float py  = (float)(h + tap / 3 - 1) + dy;
    float pxx = (float)(ww_ + tap % 3 - 1) + dx;
    float y0f = floorf(py), x0f = floorf(pxx);
    int y0 = (int)y0f, x0 = (int)x0f;
    float ly = py - y0f, lx = pxx - x0f;
    int y1 = y0 + 1, x1 = x0 + 1;
    bool vy0 = (unsigned)y0 < HH, vy1 = (unsigned)y1 < HH;
    bool vx0 = (unsigned)x0 < WW, vx1 = (unsigned)x1 < WW;
    int cy0 = min(max(y0, 0), HH - 1), cy1 = min(max(y1, 0), HH - 1);
    int cx0 = min(max(x0, 0), WW - 1), cx1 = min(max(x1, 0), WW - 1);
    unsigned i00 = cy0 * WW + cx0, i01 = cy0 * WW + cx1;
    unsigned i10 = cy1 * WW + cx0, i11 = cy1 * WW + cx1;
    float w00 = (vy0 && vx0) ? m * (1.f - ly) * (1.f - lx) : 0.f;
    float w01 = (vy0 && vx1) ? m * (1.f - ly) * lx         : 0.f;
    float w10 = (vy1 && vx0) ? m * ly * (1.f - lx)         : 0.f;
    float w11 = (vy1 && vx1) ? m * ly * lx                 : 0.f;
    sidxw[(tap * 4 + 0) * 64 + pp] = i00 | ((unsigned)f2h(w00) << 16);
    sidxw[(tap * 4 + 1) * 64 + pp] = i01 | ((unsigned)f2h(w01) << 16);
    sidxw[(tap * 4 + 2) * 64 + pp] = i10 | ((unsigned)f2h(w10) << 16);
    sidxw[(tap * 4 + 3) * 64 + pp] = i11 | ((unsigned)f2h(w11) << 16);
  }
  __syncthreads();                          // om dead after this point

  // ===== phase 3: deformable GEMM, quarter-double-buffered =====
  // acc[q][m]: oc = q*32 + nw*16 + l15, px = mw*32 + m*16 + quad*4 + reg
  f32x4 acc[4][2];
#pragma unroll
  for (int q = 0; q < 4; ++q)
#pragma unroll
    for (int m = 0; m < 2; ++m) acc[q][m] = (f32x4){0.f, 0.f, 0.f, 0.f};
  const unsigned short* xnb = xn + ((size_t)b * HWSZ) * 128;

  // half-batch gather (G = 2h, 2h+1): 8 loads, 32 VGPR of data
  auto gatherH = [&](int tap, int h, uint4 v[2][4]) {
#pragma unroll
    for (int gi = 0; gi < 2; ++gi) {
      int G = 2 * h + gi;
#pragma unroll
      for (int cr = 0; cr < 4; ++cr) {
        unsigned s = sidxw[(tap * 4 + cr) * 64 + w * 16 + G * 4 + quad];
        v[gi][cr] = *(const uint4*)(xnb + ((size_t)(s & 0xffffu) << 7) + l15 * 8);
      }
    }
  };
  auto combineH = [&](int tap, int h, uint4 v[2][4]) {
#pragma unroll
    for (int gi = 0; gi < 2; ++gi) {
      int G = 2 * h + gi;
      h2 f[4];
#pragma unroll
      for (int j = 0; j < 4; ++j) f[j] = (h2){(_Float16)0.f, (_Float16)0.f};
#pragma unroll
      for (int cr = 0; cr < 4; ++cr) {
        unsigned s = sidxw[(tap * 4 + cr) * 64 + w * 16 + G * 4 + quad];
        _Float16 wh = __builtin_bit_cast(_Float16, (unsigned short)(s >> 16));
        h2 wpk = {wh, wh};
        const h2* a = (const h2*)&v[gi][cr];
#pragma unroll
        for (int j = 0; j < 4; ++j)
          f[j] += wpk * a[j];                    // v_pk_fma_f16
      }
      *(uint4*)&val[w * 16 + G * 4 + quad][l15 * 8] =
          make_uint4(__builtin_bit_cast(unsigned, f[0]),
                     __builtin_bit_cast(unsigned, f[1]),
                     __builtin_bit_cast(unsigned, f[2]),
                     __builtin_bit_cast(unsigned, f[3]));
    }
  };
  auto stageQ = [&](unsigned* buf, int tap, int q) {
#pragma unroll
    for (int j = 0; j < 2; ++j) {
      int cc = t + 256 * j;
      int row = cc >> 4, c16 = cc & 15;
      *(uint4*)&buf[row * 68 + c16 * 4] =
          *(const uint4*)(wtb + (size_t)(q * 32 + row) * KTOT + tap * 128 + c16 * 8);
    }
  };
  auto mfmaQ = [&](const unsigned* buf, f32x4* aq, f16x8 af[2][4]) {
#pragma unroll
    for (int ks = 0; ks < 4; ++ks) {
      f16x8 bb = *(const f16x8*)&buf[(size_t)(nw * 16 + l15) * 68 +
                                     ks * 16 + quad * 4];
      aq[0] = __builtin_amdgcn_mfma_f32_16x16x32_f16(af[0][ks], bb, aq[0], 0, 0, 0);
      aq[1] = __builtin_amdgcn_mfma_f32_16x16x32_f16(af[1][ks], bb, aq[1], 0, 0, 0);
    }
  };

  // prologue: val(tap 0) + bwA q0
  {
    uint4 v0[2][4], v1[2][4];
    gatherH(0, 0, v0);
    gatherH(0, 1, v1);
    combineH(0, 0, v0);
    combineH(0, 1, v1);
    stageQ(bwA, 0, 0);
  }
  __syncthreads();

  for (int tap = 0; tap < KK; ++tap) {
    bool more = (tap + 1 < KK);
    uint4 v01[2][4], v23[2][4];
    // ---- W1: af-read | mfma q0 @ bwA | stage q1 -> bwB ----
    f16x8 af[2][4];
#pragma unroll
    for (int m = 0; m < 2; ++m)
#pragma unroll
      for (int ks = 0; ks < 4; ++ks)
        af[m][ks] =
            *(const f16x8*)&val[mw * 32 + m * 16 + l15][ks * 32 + quad * 8];
    stageQ(bwB, tap, 1);
    mfmaQ(bwA, acc[0], af);
    __syncthreads();
    // ---- W2: gather G0-G1(t+1) | mfma q1 @ bwB | stage q2 -> bwA ----
    if (more) gatherH(tap + 1, 0, v01);
    stageQ(bwA, tap, 2);
    mfmaQ(bwB, acc[1], af);
    __syncthreads();
    // ---- W3: combine G0-G1 | gather G2-G3(t+1) | mfma q2 @ bwA | stage q3 ----
    if (more) {
      combineH(tap + 1, 0, v01);
      gatherH(tap + 1, 1, v23);
    }
    stageQ(bwB, tap, 3);
    mfmaQ(bwA, acc[2], af);
    __syncthreads();
    // ---- W4: combine G2-G3 | mfma q3 @ bwB | stage q0(t+1) -> bwA ----
    if (more) {
      combineH(tap + 1, 1, v23);
      stageQ(bwA, tap + 1, 0);
    }
    mfmaQ(bwB, acc[3], af);
    if (more) __syncthreads();
  }

  // ===== phase 4: direct epilogue (reg = 4 consecutive px -> float4 store) ===
#pragma unroll
  for (int q = 0; q < 4; ++q)
#pragma unroll
    for (int m = 0; m < 2; ++m) {
      int oc = q * 32 + nw * 16 + l15;
      f32x4 a = acc[q][m];
      float db = defb[oc];
      float4 vv = make_float4(a[0] + db, a[1] + db, a[2] + db, a[3] + db);
      *(float4*)&out[((size_t)b * OUTC + oc) * HWSZ + pblk + mw * 32 +
                     m * 16 + quad * 4] = vv;
    }
}

extern "C" void kernel_launch(void* const* d_in, const int* in_sizes, int n_in,
                              void* d_out, int out_size, void* d_ws, size_t ws_size,
                              hipStream_t stream) {
  const float* x     = (const float*)d_in[0];
  const float* x2    = (const float*)d_in[1];
  const float* offw  = (const float*)d_in[2];
  const float* offb  = (const float*)d_in[3];
  const float* maskw = (const float*)d_in[4];
  const float* maskb = (const float*)d_in[5];
  const float* defw  = (const float*)d_in[6];
  const float* defb  = (const float*)d_in[7];
  float* out = (float*)d_out;

  hipLaunchKernelGGL(prep_all, dim3(1873), dim3(256), 0, stream,
                     x, x2, offw, maskw, defw, offb, maskb, d_ws);
  hipLaunchKernelGGL(fused, dim3(576), dim3(256), 0, stream, defb, d_ws, out);
}

// Round 15
// 137.530 us; speedup vs baseline: 1.1171x; 1.0070x over previous
//
#include <hip/hip_runtime.h>

// DeformConv fused fp16: r13 + lgkmcnt-only window barriers (no vmcnt drain).
// Gathers issued in window i ride across the barrier to window i+1; all
// cross-wave LDS hazards covered by lgkmcnt(0)+s_barrier (audited).
// B=4, C=128, H=W=96, O=128, 3x3 s1 p1 d1, G=1.
#define CIN   128
#define HH    96
#define WW    96
#define OUTC  128
#define HWSZ  9216
#define KK    9
#define KTOT  1152        // k' = tap*128 + c (tap-major)

typedef _Float16 f16x8 __attribute__((ext_vector_type(8)));
typedef _Float16 h2    __attribute__((ext_vector_type(2)));
typedef float    f32x4 __attribute__((ext_vector_type(4)));

__device__ __forceinline__ unsigned short f2h(float f) {
  _Float16 h = (_Float16)f;                      // v_cvt_f16_f32 (RNE)
  return __builtin_bit_cast(unsigned short, h);
}
// pack two floats to f16x2 (RTZ) : 1 VALU
__device__ __forceinline__ unsigned pack_h(float v0, float v1) {
  auto r = __builtin_amdgcn_cvt_pkrtz(v0, v1);   // lo = v0, hi = v1
  return __builtin_bit_cast(unsigned, r);
}

// barrier that waits only on LDS ops (ds_read/ds_write) -- vmcnt (in-flight
// global gathers, wave-private VGPR dests) intentionally NOT drained.
#define LGKM_BAR()                                           \
  do {                                                       \
    asm volatile("s_waitcnt lgkmcnt(0)" ::: "memory");       \
    __builtin_amdgcn_s_barrier();                            \
    asm volatile("" ::: "memory");                           \
  } while (0)

// ws layout (u16 offsets):
//   wtb   f16[128][1152] @ 0         (k' = tap*128+c)
//   wt2b  f16[32][1152]  @ 147456    (oc 0-17 offset, 18-26 mask, 27-31 zero)
//   bias32 f32[32]       @ 184320
//   xn    f16[4][9216][128] @ 184384 (NHWC)
//   x2n   f16[4][9216][128] @ 184384+4718592
#define WT2B_O 147456
#define BIAS_O 184320
#define XN_O   184384
#define X2N_O  (184384 + 4718592)

// Combined prep: blocks [0,1152) = NCHW->NHWC f16 transpose of x/x2
// (float4 loads: 4 px/lane, 16 c-rows/pass; uint4 stores);
// blocks [1152,1873) = weight reorder/cast.
__global__ __launch_bounds__(256) void prep_all(
    const float* __restrict__ x, const float* __restrict__ x2,
    const float* __restrict__ offw, const float* __restrict__ maskw,
    const float* __restrict__ defw, const float* __restrict__ offb,
    const float* __restrict__ maskb, void* __restrict__ wsv) {
  int bid = blockIdx.x;
  int t = threadIdx.x;
  if (bid < 1152) {
    // u16 tile[64 px][136] (word stride 68): word (c>>1) holds {c, c+1}
    __shared__ unsigned short tile[64][136];
    int tsel = bid / 576;
    int rem = bid - tsel * 576;
    int b = rem / 144;
    int hw0 = (rem % 144) * 64;
    const float* src = tsel ? x2 : x;
    unsigned short* dst = (unsigned short*)wsv + (tsel ? X2N_O : XN_O);
    unsigned* tw = (unsigned*)&tile[0][0];
    int c2  = t & 15;        // channel-pair index within pass
    int px4 = t >> 4;        // 0..15 -> px = px4*4..+3
#pragma unroll
    for (int pass = 0; pass < 4; ++pass) {
      int c = pass * 32 + c2 * 2;
      const float* r0 = src + ((size_t)(b * CIN + c)) * HWSZ + hw0 + px4 * 4;
      float4 f0 = *(const float4*)r0;          // 4 px of channel c
      float4 f1 = *(const float4*)(r0 + HWSZ); // 4 px of channel c+1
      int wb = pass * 16 + c2;                 // = c>>1
      tw[(px4 * 4 + 0) * 68 + wb] = pack_h(f0.x, f1.x);
      tw[(px4 * 4 + 1) * 68 + wb] = pack_h(f0.y, f1.y);
      tw[(px4 * 4 + 2) * 68 + wb] = pack_h(f0.z, f1.z);
      tw[(px4 * 4 + 3) * 68 + wb] = pack_h(f0.w, f1.w);
    }
    __syncthreads();
    unsigned* drow = (unsigned*)(dst + ((size_t)(b * HWSZ + hw0)) * 128);
    int w4 = t & 15, pxr = t >> 4;
#pragma unroll
    for (int pass = 0; pass < 4; ++pass) {
      int px = pass * 16 + pxr;
      uint4 v = *(const uint4*)&tw[px * 68 + w4 * 4];
      *(uint4*)&drow[(size_t)px * 64 + w4 * 4] = v;
    }
    return;
  }
  unsigned short* wtb  = (unsigned short*)wsv;
  unsigned short* wt2b = wtb + WT2B_O;
  float* bias32 = (float*)(wtb + BIAS_O);
  int idx = (bid - 1152) * 256 + t;
  if (idx < OUTC * KTOT) {
    int o = idx / KTOT, r = idx - o * KTOT;
    int c = r / KK, tap = r - c * KK;
    wtb[o * KTOT + tap * 128 + c] = f2h(defw[idx]);
  } else if (idx < OUTC * KTOT + 32 * KTOT) {
    int j = idx - OUTC * KTOT;
    int oc = j / KTOT, r = j - oc * KTOT;
    int c = r / KK, tap = r - c * KK;
    float v = 0.f;
    if (oc < 18)      v = offw[j];
    else if (oc < 27) v = maskw[j - 18 * KTOT];
    wt2b[oc * KTOT + tap * 128 + c] = f2h(v);
  } else if (idx < OUTC * KTOT + 32 * KTOT + 32) {
    int j = idx - OUTC * KTOT - 32 * KTOT;
    float v = 0.f;
    if (j < 18) v = offb[j]; else if (j < 27) v = maskb[j - 18];
    bias32[j] = v;
  }
}

// Fused: block = 64-px strip.
// Gather roles: wave w gathers px strip w*16..+15, lanes (quad = px-in-group,
// l15 = channel octet) -> full 256B row reads; combine via v_pk_fma_f16 -> val.
// Phase 1: pipelined, 1 LGKM_BAR/tap (wave-private val; dbuf B-stage).
// Phase 3: quarter-double-buffered bwA/bwB (8.7KB), 4 windows/tap mixing
// mfma + stage + gather/combine; windows end with LGKM_BAR so the gathers
// issued this window stay in flight across the barrier (wave-private VGPR
// dests; compiler inserts the vmcnt wait at the combine that consumes them).
// om aliases val; direct f32x4 epilogue. LDS 44KB -> 3 blocks/CU.
__global__ __launch_bounds__(256, 3) void fused(
    const float* __restrict__ defb, const void* __restrict__ wsv,
    float* __restrict__ out) {
  const unsigned short* wtb  = (const unsigned short*)wsv;
  const unsigned short* wt2b = wtb + WT2B_O;
  const float* bias32 = (const float*)(wtb + BIAS_O);
  const unsigned short* xn  = wtb + XN_O;
  const unsigned short* x2n = wtb + X2N_O;

  __shared__ unsigned bwA[32 * 68];        // 8.7 KB: B quarter buffer A
  __shared__ unsigned bwB[32 * 68];        // 8.7 KB: B quarter buffer B
  __shared__ unsigned short val[64][136];  // 17.4 KB: A tile (f16), pad 136
  __shared__ unsigned sidxw[KK * 4 * 64];  // 9.2 KB: [(tap*4+cr)*64+px] idx|w<<16
  float* om = (float*)&val[0][0];          // alias: om[oc*68+pp], 8.7 KB

  int t = threadIdx.x;
  int w = t >> 6;
  int mw = w & 1, nw = w >> 1;             // phase-3 wave grid
  int l15 = t & 15, quad = (t >> 4) & 3;
  int rb = blockIdx.x;
  int bid = (rb & 7) * 72 + (rb >> 3);     // XCD swizzle
  int b = bid / 144;
  int pblk = (bid % 144) * 64;

  // gather-role pixels: px = 16w + G*4 + quad
  int phg[4], pwg[4];
#pragma unroll
  for (int G = 0; G < 4; ++G) {
    int p = pblk + w * 16 + G * 4 + quad;
    phg[G] = p / WW;
    pwg[G] = p - phg[G] * WW;
  }

  // ===== phase 1: offset/mask GEMM, pipelined (1 barrier/tap) =====
  f32x4 oa0 = {0.f, 0.f, 0.f, 0.f};
  f32x4 oa1 = {0.f, 0.f, 0.f, 0.f};
  const unsigned short* x2nb = x2n + ((size_t)b * HWSZ) * 128;
  auto gather1 = [&](int tap, uint4 vG[4]) {
    int ky = tap / 3 - 1, kx = tap % 3 - 1;
#pragma unroll
    for (int G = 0; G < 4; ++G) {
      int y = phg[G] + ky, xx = pwg[G] + kx;
      bool ok = ((unsigned)y < HH) && ((unsigned)xx < WW);
      int pos = ok ? (y * WW + xx) : 0;
      uint4 v = *(const uint4*)(x2nb + ((size_t)pos << 7) + l15 * 8);
      vG[G] = ok ? v : make_uint4(0u, 0u, 0u, 0u);
    }
  };
  auto stage1 = [&](unsigned* buf, int tap) {
#pragma unroll
    for (int j = 0; j < 2; ++j) {          // stage 32 oc rows x 64 dw
      int cc = t + 256 * j;
      int row = cc >> 4, c16 = cc & 15;
      *(uint4*)&buf[row * 68 + c16 * 4] =
          *(const uint4*)(wt2b + (size_t)row * KTOT + tap * 128 + c16 * 8);
    }
  };
  auto valw1 = [&](uint4 vG[4]) {
#pragma unroll
    for (int G = 0; G < 4; ++G)
      *(uint4*)&val[w * 16 + G * 4 + quad][l15 * 8] = vG[G];
  };
  {
    uint4 vG[4];
    gather1(0, vG);
    stage1(bwA, 0);
    valw1(vG);
  }
  LGKM_BAR();
  for (int tap = 0; tap < KK; ++tap) {
    unsigned* cur = (tap & 1) ? bwB : bwA;
    unsigned* nxt = (tap & 1) ? bwA : bwB;
    uint4 vN[4];
    bool more = (tap + 1 < KK);
    if (more) {
      gather1(tap + 1, vN);                // issue next-tap gathers first
      stage1(nxt, tap + 1);                // stage next-tap B half
    }
#pragma unroll
    for (int ks = 0; ks < 4; ++ks) {
      f16x8 af = *(const f16x8*)&val[w * 16 + l15][ks * 32 + quad * 8];
      f16x8 b0 = *(const f16x8*)&cur[(size_t)l15 * 68 + ks * 16 + quad * 4];
      f16x8 b1 = *(const f16x8*)&cur[(size_t)(l15 + 16) * 68 + ks * 16 + quad * 4];
      oa0 = __builtin_amdgcn_mfma_f32_16x16x32_f16(af, b0, oa0, 0, 0, 0);
      oa1 = __builtin_amdgcn_mfma_f32_16x16x32_f16(af, b1, oa1, 0, 0, 0);
    }
    if (more) valw1(vN);                   // own rows, after af reads (in-order)
    LGKM_BAR();
  }
  // dump om (+bias) into val-alias: col=px-in-block, row=oc.
#pragma unroll
  for (int nt = 0; nt < 2; ++nt) {
    f32x4 a = nt ? oa1 : oa0;
    int oc = nt * 16 + l15;
    float bia = bias32[oc];
#pragma unroll
    for (int r = 0; r < 4; ++r)
      om[oc * 68 + w * 16 + quad * 4 + r] = a[r] + bia;
  }
  __syncthreads();

  // ===== phase 2: bilinear params -> sidxw =====
  for (int e = t; e < KK * 64; e += 256) {
    int tap = e >> 6, pp = e & 63;
    int gp2 = pblk + pp;
    int h = gp2 / WW, ww_ = gp2 % WW;
    float dy = om[2 * tap * 68 + pp], dx = om[(2 * tap + 1) * 68 + pp];
    float mr = om[(18 + tap) * 68 + pp];
    float m = 1.f / (1.f + __expf(-mr));
    float py  = (float)(h + tap / 3 - 1) + dy;
    float pxx = (float)(ww_ + tap % 3 - 1) + dx;
    float y0f = floorf(py), x0f = floorf(pxx);
    int y0 = (int)y0f, x0 = (int)x0f;
    float ly = py - y0f, lx = pxx - x0f;
    int y1 = y0 + 1, x1 = x0 + 1;
    bool vy0 = (unsigned)y0 < HH, vy1 = (unsigned)y1 < HH;
    bool vx0 = (unsigned)x0 < WW, vx1 = (unsigned)x1 < WW;
    int cy0 = min(max(y0, 0), HH - 1), cy1 = min(max(y1, 0), HH - 1);
    int cx0 = min(max(x0, 0), WW - 1), cx1 = min(max(x1, 0), WW - 1);
    unsigned i00 = cy0 * WW + cx0, i01 = cy0 * WW + cx1;
    unsigned i10 = cy1 * WW + cx0, i11 = cy1 * WW + cx1;
    float w00 = (vy0 && vx0) ? m * (1.f - ly) * (1.f - lx) : 0.f;
    float w01 = (vy0 && vx1) ? m * (1.f - ly) * lx         : 0.f;
    float w10 = (vy1 && vx0) ? m * ly * (1.f - lx)         : 0.f;
    float w11 = (vy1 && vx1) ? m * ly * lx                 : 0.f;
    sidxw[(tap * 4 + 0) * 64 + pp] = i00 | ((unsigned)f2h(w00) << 16);
    sidxw[(tap * 4 + 1) * 64 + pp] = i01 | ((unsigned)f2h(w01) << 16);
    sidxw[(tap * 4 + 2) * 64 + pp] = i10 | ((unsigned)f2h(w10) << 16);
    sidxw[(tap * 4 + 3) * 64 + pp] = i11 | ((unsigned)f2h(w11) << 16);
  }
  __syncthreads();                          // om dead after this point

  // ===== phase 3: deformable GEMM, quarter-double-buffered =====
  // acc[q][m]: oc = q*32 + nw*16 + l15, px = mw*32 + m*16 + quad*4 + reg
  f32x4 acc[4][2];
#pragma unroll
  for (int q = 0; q < 4; ++q)
#pragma unroll
    for (int m = 0; m < 2; ++m) acc[q][m] = (f32x4){0.f, 0.f, 0.f, 0.f};
  const unsigned short* xnb = xn + ((size_t)b * HWSZ) * 128;

  // half-batch gather (G = 2h, 2h+1): 8 loads, 32 VGPR of data
  auto gatherH = [&](int tap, int h, uint4 v[2][4]) {
#pragma unroll
    for (int gi = 0; gi < 2; ++gi) {
      int G = 2 * h + gi;
#pragma unroll
      for (int cr = 0; cr < 4; ++cr) {
        unsigned s = sidxw[(tap * 4 + cr) * 64 + w * 16 + G * 4 + quad];
        v[gi][cr] = *(const uint4*)(xnb + ((size_t)(s & 0xffffu) << 7) + l15 * 8);
      }
    }
  };
  auto combineH = [&](int tap, int h, uint4 v[2][4]) {
#pragma unroll
    for (int gi = 0; gi < 2; ++gi) {
      int G = 2 * h + gi;
      h2 f[4];
#pragma unroll
      for (int j = 0; j < 4; ++j) f[j] = (h2){(_Float16)0.f, (_Float16)0.f};
#pragma unroll
      for (int cr = 0; cr < 4; ++cr) {
        unsigned s = sidxw[(tap * 4 + cr) * 64 + w * 16 + G * 4 + quad];
        _Float16 wh = __builtin_bit_cast(_Float16, (unsigned short)(s >> 16));
        h2 wpk = {wh, wh};
        const h2* a = (const h2*)&v[gi][cr];
#pragma unroll
        for (int j = 0; j < 4; ++j)
          f[j] += wpk * a[j];                    // v_pk_fma_f16
      }
      *(uint4*)&val[w * 16 + G * 4 + quad][l15 * 8] =
          make_uint4(__builtin_bit_cast(unsigned, f[0]),
                     __builtin_bit_cast(unsigned, f[1]),
                     __builtin_bit_cast(unsigned, f[2]),
                     __builtin_bit_cast(unsigned, f[3]));
    }
  };
  auto stageQ = [&](unsigned* buf, int tap, int q) {
#pragma unroll
    for (int j = 0; j < 2; ++j) {
      int cc = t + 256 * j;
      int row = cc >> 4, c16 = cc & 15;
      *(uint4*)&buf[row * 68 + c16 * 4] =
          *(const uint4*)(wtb + (size_t)(q * 32 + row) * KTOT + tap * 128 + c16 * 8);
    }
  };
  auto mfmaQ = [&](const unsigned* buf, f32x4* aq, f16x8 af[2][4]) {
#pragma unroll
    for (int ks = 0; ks < 4; ++ks) {
      f16x8 bb = *(const f16x8*)&buf[(size_t)(nw * 16 + l15) * 68 +
                                     ks * 16 + quad * 4];
      aq[0] = __builtin_amdgcn_mfma_f32_16x16x32_f16(af[0][ks], bb, aq[0], 0, 0, 0);
      aq[1] = __builtin_amdgcn_mfma_f32_16x16x32_f16(af[1][ks], bb, aq[1], 0, 0, 0);
    }
  };

  // prologue: val(tap 0) + bwA q0
  {
    uint4 v0[2][4], v1[2][4];
    gatherH(0, 0, v0);
    gatherH(0, 1, v1);
    combineH(0, 0, v0);
    combineH(0, 1, v1);
    stageQ(bwA, 0, 0);
  }
  LGKM_BAR();

  for (int tap = 0; tap < KK; ++tap) {
    bool more = (tap + 1 < KK);
    uint4 v01[2][4], v23[2][4];
    // ---- W1: af-read | mfma q0 @ bwA | stage q1 -> bwB ----
    f16x8 af[2][4];
#pragma unroll
    for (int m = 0; m < 2; ++m)
#pragma unroll
      for (int ks = 0; ks < 4; ++ks)
        af[m][ks] =
            *(const f16x8*)&val[mw * 32 + m * 16 + l15][ks * 32 + quad * 8];
    stageQ(bwB, tap, 1);
    mfmaQ(bwA, acc[0], af);
    LGKM_BAR();
    // ---- W2: gather G0-G1(t+1) | mfma q1 @ bwB | stage q2 -> bwA ----
    if (more) gatherH(tap + 1, 0, v01);    // rides across barrier (VGPR dest)
    stageQ(bwA, tap, 2);
    mfmaQ(bwB, acc[1], af);
    LGKM_BAR();
    // ---- W3: combine G0-G1 | gather G2-G3(t+1) | mfma q2 @ bwA | stage q3 ----
    if (more) {
      combineH(tap + 1, 0, v01);
      gatherH(tap + 1, 1, v23);
    }
    stageQ(bwB, tap, 3);
    mfmaQ(bwA, acc[2], af);
    LGKM_BAR();
    // ---- W4: combine G2-G3 | mfma q3 @ bwB | stage q0(t+1) -> bwA ----
    if (more) {
      combineH(tap + 1, 1, v23);
      stageQ(bwA, tap + 1, 0);
    }
    mfmaQ(bwB, acc[3], af);
    if (more) LGKM_BAR();
  }

  // ===== phase 4: direct epilogue (reg = 4 consecutive px -> float4 store) ===
#pragma unroll
  for (int q = 0; q < 4; ++q)
#pragma unroll
    for (int m = 0; m < 2; ++m) {
      int oc = q * 32 + nw * 16 + l15;
      f32x4 a = acc[q][m];
      float db = defb[oc];
      float4 vv = make_float4(a[0] + db, a[1] + db, a[2] + db, a[3] + db);
      *(float4*)&out[((size_t)b * OUTC + oc) * HWSZ + pblk + mw * 32 +
                     m * 16 + quad * 4] = vv;
    }
}

extern "C" void kernel_launch(void* const* d_in, const int* in_sizes, int n_in,
                              void* d_out, int out_size, void* d_ws, size_t ws_size,
                              hipStream_t stream) {
  const float* x     = (const float*)d_in[0];
  const float* x2    = (const float*)d_in[1];
  const float* offw  = (const float*)d_in[2];
  const float* offb  = (const float*)d_in[3];
  const float* maskw = (const float*)d_in[4];
  const float* maskb = (const float*)d_in[5];
  const float* defw  = (const float*)d_in[6];
  const float* defb  = (const float*)d_in[7];
  float* out = (float*)d_out;

  hipLaunchKernelGGL(prep_all, dim3(1873), dim3(256), 0, stream,
                     x, x2, offw, maskw, defw, offb, maskb, d_ws);
  hipLaunchKernelGGL(fused, dim3(576), dim3(256), 0, stream, defb, d_ws, out);
}